// Round 10
// baseline (39.256 us; speedup 1.0000x reference)
//
#include <hip/hip_runtime.h>

#define NJ     62
#define NV     14522
#define NCORE  28
#define KPAD   256    // 62*4 = 248 padded to 256
#define OUTF   (NV * 3)        // 43566
#define MT     908             // m-tiles of 16 rows
#define NSTR   192             // stripes: 140 of 5 tiles, 52 of 4

typedef __attribute__((ext_vector_type(8))) short short8v;
typedef __attribute__((ext_vector_type(4))) short short4v;
typedef __attribute__((ext_vector_type(4))) float floatx4;
typedef __attribute__((ext_vector_type(2))) float floatx2;

static __device__ inline short f2bf(float x) {
    unsigned u = __float_as_uint(x);
    unsigned r = (u + 0x7fffu + ((u >> 16) & 1u)) >> 16;
    return (short)r;
}

// pack 8 floats -> 8 bf16 (RNE) via v_cvt_pk_bf16_f32 (pure, schedulable asm)
static __device__ inline short8v pack8(float a0, float a1, float a2, float a3,
                                       float a4, float a5, float a6, float a7) {
    union { unsigned u[4]; short8v v; } p;
    asm("v_cvt_pk_bf16_f32 %0, %1, %2" : "=v"(p.u[0]) : "v"(a0), "v"(a1));
    asm("v_cvt_pk_bf16_f32 %0, %1, %2" : "=v"(p.u[1]) : "v"(a2), "v"(a3));
    asm("v_cvt_pk_bf16_f32 %0, %1, %2" : "=v"(p.u[2]) : "v"(a4), "v"(a5));
    asm("v_cvt_pk_bf16_f32 %0, %1, %2" : "=v"(p.u[3]) : "v"(a6), "v"(a7));
    return p.v;
}

// ---------------------------------------------------------------------------
// Kernel 1: forward kinematics only. 64 blocks x 256 thr; wave w = batch
// blockIdx*4+w. Writes Jout (fp32) and Bt[(b*3+i)*KPAD + 4k+j] = G' (bf16).
// ---------------------------------------------------------------------------
__global__ __launch_bounds__(256) void fk_kernel(
    const float* __restrict__ thetas, const float* __restrict__ blc,
    const float* __restrict__ cbl, const float* __restrict__ trans,
    const float* __restrict__ scale, const float* __restrict__ tpose,
    const int* __restrict__ parents, const int* __restrict__ mapper,
    short* __restrict__ Bt, float* __restrict__ Jout)
{
    __shared__ float Asm[4][NJ][12];
    __shared__ float Gsm[4][NJ][12];

    const int w = threadIdx.x >> 6;
    const int b = blockIdx.x * 4 + w;
    const int k = threadIdx.x & 63;
    int p = 0;

    if (k < NJ) {
        p = parents[k];
        const float tz = thetas[(b * NJ + k) * 3 + 0];
        const float ty = thetas[(b * NJ + k) * 3 + 1];
        const float tx = thetas[(b * NJ + k) * 3 + 2];
        const float cx = cosf(tx), sx = sinf(tx);
        const float cy = cosf(ty), sy = sinf(ty);
        const float cz = cosf(tz), sz = sinf(tz);
        const float r00 = cz * cy;
        const float r01 = cz * sy * sx - sz * cx;
        const float r02 = sz * sx + cz * sy * cx;
        const float r10 = sz * cy;
        const float r11 = cz * cx + sz * sy * sx;
        const float r12 = sz * sy * cx - cz * sx;
        const float r20 = -sy;
        const float r21 = cy * sx;
        const float r22 = cy * cx;

        float f;
        const int m = mapper[k];
        if (k == 0)        f = 1.0f;
        else if (k == 1)   f = cbl[b];
        else if (m < 0)    f = 1.0f;
        else               f = 2.0f / (1.0f + expf(-blc[b * NCORE + m] * 0.2f));

        float ox, oy, oz;
        if (k == 0) {
            ox = tpose[0]; oy = tpose[1]; oz = tpose[2];
        } else {
            ox = (tpose[k * 3 + 0] - tpose[p * 3 + 0]) * f;
            oy = (tpose[k * 3 + 1] - tpose[p * 3 + 1]) * f;
            oz = (tpose[k * 3 + 2] - tpose[p * 3 + 2]) * f;
        }
        Asm[w][k][0] = r00; Asm[w][k][1] = r01; Asm[w][k][2]  = r02; Asm[w][k][3]  = ox;
        Asm[w][k][4] = r10; Asm[w][k][5] = r11; Asm[w][k][6]  = r12; Asm[w][k][7]  = oy;
        Asm[w][k][8] = r20; Asm[w][k][9] = r21; Asm[w][k][10] = r22; Asm[w][k][11] = oz;
    }
    __syncthreads();

    if (k == 0) {
        #pragma unroll
        for (int j = 0; j < 12; ++j) Gsm[w][0][j] = Asm[w][0][j];
    }
    __syncthreads();

    const int depth = (k < NJ) ? (31 - __clz((unsigned)(k + 1))) : 99;
    for (int d = 1; d <= 5; ++d) {
        if (depth == d) {
            float gp[12], a[12], g[12];
            #pragma unroll
            for (int j = 0; j < 12; ++j) { gp[j] = Gsm[w][p][j]; a[j] = Asm[w][k][j]; }
            #pragma unroll
            for (int i = 0; i < 3; ++i) {
                #pragma unroll
                for (int j = 0; j < 4; ++j) {
                    float s = (j == 3) ? gp[i * 4 + 3] : 0.0f;
                    s = fmaf(gp[i * 4 + 0], a[0 * 4 + j], s);
                    s = fmaf(gp[i * 4 + 1], a[1 * 4 + j], s);
                    s = fmaf(gp[i * 4 + 2], a[2 * 4 + j], s);
                    g[i * 4 + j] = s;
                }
            }
            #pragma unroll
            for (int j = 0; j < 12; ++j) Gsm[w][k][j] = g[j];
        }
        __syncthreads();
    }

    if (k < NJ) {
        float g[12];
        #pragma unroll
        for (int j = 0; j < 12; ++j) g[j] = Gsm[w][k][j];
        const float jx = tpose[k * 3 + 0];
        const float jy = tpose[k * 3 + 1];
        const float jz = tpose[k * 3 + 2];
        const float s  = scale[b];
        Jout[(b * NJ + k) * 3 + 0] = fmaf(g[3],  s, trans[b * 3 + 0]);
        Jout[(b * NJ + k) * 3 + 1] = fmaf(g[7],  s, trans[b * 3 + 1]);
        Jout[(b * NJ + k) * 3 + 2] = fmaf(g[11], s, trans[b * 3 + 2]);
        float np[3];
        np[0] = g[3]  - (g[0] * jx + g[1] * jy + g[2]  * jz);
        np[1] = g[7]  - (g[4] * jx + g[5] * jy + g[6]  * jz);
        np[2] = g[11] - (g[8] * jx + g[9] * jy + g[10] * jz);
        #pragma unroll
        for (int i = 0; i < 3; ++i) {
            short4v o;
            o[0] = f2bf(g[i * 4 + 0]);
            o[1] = f2bf(g[i * 4 + 1]);
            o[2] = f2bf(g[i * 4 + 2]);
            o[3] = f2bf(np[i]);
            *(short4v*)&Bt[(size_t)(b * 3 + i) * KPAD + k * 4] = o;
        }
        if (k == 0) {   // zero K padding cols 248..255
            short4v z = {0, 0, 0, 0};
            #pragma unroll
            for (int i = 0; i < 3; ++i) {
                *(short4v*)&Bt[(size_t)(b * 3 + i) * KPAD + 248] = z;
                *(short4v*)&Bt[(size_t)(b * 3 + i) * KPAD + 252] = z;
            }
        }
    }
}

// ---------------------------------------------------------------------------
// Kernel 2: GEMM + epilogue, A built on the fly (r9 structure), occupancy
// experiment: 192 stripes x 16 y-groups = 3072 waves, grid 768 = 3 blocks/CU
// = 12 waves/CU (3/SIMD), launch_bounds(256,3) to cap VGPR at 168.
// Everything else identical to r9.
// ---------------------------------------------------------------------------
__global__ __launch_bounds__(256, 3) void gemm_skin(
    const float* __restrict__ W,      // (V, 62) fp32
    const float* __restrict__ vt,     // (V, 3)  fp32
    const short* __restrict__ Bt,     // (768, KPAD) bf16
    const float* __restrict__ scale,  // (B,)
    const float* __restrict__ trans,  // (B*3,)
    float* __restrict__ out)          // (B, V, 3)
{
    __shared__ __align__(16) float epi_all[4 * 800];   // 12.8 KB

    const int tid  = threadIdx.x;
    const int wave = tid >> 6;
    const int lane = tid & 63;
    const int lrow = lane & 15;
    const int lk   = lane >> 4;
    const int y     = blockIdx.x >> 6;          // 0..11? no: 768/48 -> y = bid/48
    // 768 blocks = 16 y-groups x 48 inner
    const int yy    = blockIdx.x / 48;          // 0..15
    const int inner = blockIdx.x - yy * 48;     // 0..47
    const int s     = inner * 4 + wave;         // stripe 0..191
    const int start  = s * 4 + (s < 140 ? s : 140);
    const int ntiles = 4 + (s < 140 ? 1 : 0);
    const int b0 = yy * 16;
    (void)y;
    float* epi = epi_all + wave * 800;          // 16 regions x 50 floats

    // ---- B slab -> registers, straight from global (L2-hot, loaded once)
    short8v breg[3][8];
    {
        const short* Bw = Bt + (size_t)yy * 48 * KPAD;
        #pragma unroll
        for (int nt = 0; nt < 3; ++nt)
            #pragma unroll
            for (int k8 = 0; k8 < 8; ++k8)
                breg[nt][k8] = *(const short8v*)(Bw + (nt * 16 + lrow) * KPAD
                                                 + (k8 * 4 + lk) * 8);
    }

    // ---- per-thread invariants
    float sv[3], tv[3]; int bl3[3], ii3[3];
    #pragma unroll
    for (int nt = 0; nt < 3; ++nt) {
        const int n_loc = nt * 16 + lrow;
        bl3[nt] = n_loc / 3; ii3[nt] = n_loc - bl3[nt] * 3;
        sv[nt] = scale[b0 + bl3[nt]];
        tv[nt] = trans[(b0 + bl3[nt]) * 3 + ii3[nt]];
    }
    size_t sbase[6]; int loff[6], jj[6];
    #pragma unroll
    for (int it = 0; it < 6; ++it) {
        const int idx = it * 64 + lane;
        const int r = idx / 24, j = idx - r * 24;   // region, float2 index
        sbase[it] = (size_t)(b0 + r) * OUTF + 2 * j;
        loff[it]  = r * 50 + 2 * j;
        jj[it]    = j;
    }

    for (int t = 0; t < ntiles; ++t) {
        const int mtile = start + t;
        int vrow = mtile * 16 + lrow;
        if (vrow > NV - 1) vrow = NV - 1;           // pad rows: never stored
        const float hx = vt[vrow * 3 + 0];
        const float hy = vt[vrow * 3 + 1];
        const float hz = vt[vrow * 3 + 2];
        const float* Wr = W + (size_t)vrow * NJ;

        floatx4 acc[3];
        #pragma unroll
        for (int nt = 0; nt < 3; ++nt) acc[nt] = (floatx4){0.f, 0.f, 0.f, 0.f};

        #pragma unroll
        for (int k8 = 0; k8 < 8; ++k8) {
            const int j0 = k8 * 8 + lk * 2;         // joint pair (j0, j0+1)
            float w0 = 0.f, w1 = 0.f;
            if (j0 < NJ) {                          // j0==62 only for lk=3,k8=7
                const floatx2 wv = *(const floatx2*)(Wr + j0);  // 8B-aligned
                w0 = wv[0]; w1 = wv[1];
            }
            const short8v a = pack8(w0 * hx, w0 * hy, w0 * hz, w0,
                                    w1 * hx, w1 * hy, w1 * hz, w1);
            #pragma unroll
            for (int nt = 0; nt < 3; ++nt)
                acc[nt] = __builtin_amdgcn_mfma_f32_16x16x32_bf16(
                    a, breg[nt][k8], acc[nt], 0, 0, 0);
        }

        // ---- epilogue transpose (wave-private region; compiler inserts waits)
        #pragma unroll
        for (int nt = 0; nt < 3; ++nt) {
            #pragma unroll
            for (int r = 0; r < 4; ++r)
                epi[bl3[nt] * 50 + (lk * 4 + r) * 3 + ii3[nt]] =
                    fmaf(acc[nt][r], sv[nt], tv[nt]);
        }

        // ---- coalesced stores: 16 regions x 24 float2, consecutive across t
        const int m48 = mtile * 48;
        const bool edge = (m48 + 48 > OUTF);
        #pragma unroll
        for (int it = 0; it < 6; ++it) {
            const floatx2 val = *(const floatx2*)&epi[loff[it]];
            if (!edge || m48 + 2 * jj[it] + 1 < OUTF)
                *(floatx2*)&out[sbase[it] + m48] = val;
        }
    }
}

extern "C" void kernel_launch(void* const* d_in, const int* in_sizes, int n_in,
                              void* d_out, int out_size, void* d_ws, size_t ws_size,
                              hipStream_t stream)
{
    const float* thetas  = (const float*)d_in[0];
    const float* blc     = (const float*)d_in[1];
    const float* cbl     = (const float*)d_in[2];
    const float* trans   = (const float*)d_in[3];
    const float* scale   = (const float*)d_in[4];
    const float* vtempl  = (const float*)d_in[5];
    const float* tpose   = (const float*)d_in[6];
    const float* weights = (const float*)d_in[7];
    const int*   parents = (const int*)d_in[8];
    const int*   mapper  = (const int*)d_in[9];

    float* out  = (float*)d_out;
    float* Jout = out + (size_t)256 * NV * 3;

    short* Bt = (short*)d_ws;                    // 768*KPAD bf16 = 0.39 MB

    fk_kernel<<<64, 256, 0, stream>>>(thetas, blc, cbl, trans, scale, tpose,
                                      parents, mapper, Bt, Jout);
    gemm_skin<<<768, 256, 0, stream>>>(weights, vtempl, Bt, scale, trans, out);
}

// Round 11
// 30.815 us; speedup vs baseline: 1.2739x; 1.2739x over previous
//
#include <hip/hip_runtime.h>

#define NJ     62
#define NV     14522
#define NCORE  28
#define KPAD   256    // 62*4 = 248 padded to 256
#define OUTF   (NV * 3)        // 43566
#define MT     908             // m-tiles of 16 rows

typedef __attribute__((ext_vector_type(8))) short short8v;
typedef __attribute__((ext_vector_type(4))) short short4v;
typedef __attribute__((ext_vector_type(4))) float floatx4;
typedef __attribute__((ext_vector_type(2))) float floatx2;

static __device__ inline short f2bf(float x) {
    unsigned u = __float_as_uint(x);
    unsigned r = (u + 0x7fffu + ((u >> 16) & 1u)) >> 16;
    return (short)r;
}

// pack 8 floats -> 8 bf16 (RNE) via v_cvt_pk_bf16_f32
static __device__ inline short8v pack8(float a0, float a1, float a2, float a3,
                                       float a4, float a5, float a6, float a7) {
    union { unsigned u[4]; short8v v; } p;
    asm("v_cvt_pk_bf16_f32 %0, %1, %2" : "=v"(p.u[0]) : "v"(a0), "v"(a1));
    asm("v_cvt_pk_bf16_f32 %0, %1, %2" : "=v"(p.u[1]) : "v"(a2), "v"(a3));
    asm("v_cvt_pk_bf16_f32 %0, %1, %2" : "=v"(p.u[2]) : "v"(a4), "v"(a5));
    asm("v_cvt_pk_bf16_f32 %0, %1, %2" : "=v"(p.u[3]) : "v"(a6), "v"(a7));
    return p.v;
}

// ---------------------------------------------------------------------------
// Kernel 1: forward kinematics. 64 blocks x 256 thr; wave w = batch
// blockIdx*4+w. Writes Jout (fp32) and Bt[(b*3+i)*KPAD + 4k+j] = G' (bf16).
// ---------------------------------------------------------------------------
__global__ __launch_bounds__(256) void fk_kernel(
    const float* __restrict__ thetas, const float* __restrict__ blc,
    const float* __restrict__ cbl, const float* __restrict__ trans,
    const float* __restrict__ scale, const float* __restrict__ tpose,
    const int* __restrict__ parents, const int* __restrict__ mapper,
    short* __restrict__ Bt, float* __restrict__ Jout)
{
    __shared__ float Asm[4][NJ][12];
    __shared__ float Gsm[4][NJ][12];

    const int w = threadIdx.x >> 6;
    const int b = blockIdx.x * 4 + w;
    const int k = threadIdx.x & 63;
    int p = 0;

    if (k < NJ) {
        p = parents[k];
        const float tz = thetas[(b * NJ + k) * 3 + 0];
        const float ty = thetas[(b * NJ + k) * 3 + 1];
        const float tx = thetas[(b * NJ + k) * 3 + 2];
        const float cx = cosf(tx), sx = sinf(tx);
        const float cy = cosf(ty), sy = sinf(ty);
        const float cz = cosf(tz), sz = sinf(tz);
        const float r00 = cz * cy;
        const float r01 = cz * sy * sx - sz * cx;
        const float r02 = sz * sx + cz * sy * cx;
        const float r10 = sz * cy;
        const float r11 = cz * cx + sz * sy * sx;
        const float r12 = sz * sy * cx - cz * sx;
        const float r20 = -sy;
        const float r21 = cy * sx;
        const float r22 = cy * cx;

        float f;
        const int m = mapper[k];
        if (k == 0)        f = 1.0f;
        else if (k == 1)   f = cbl[b];
        else if (m < 0)    f = 1.0f;
        else               f = 2.0f / (1.0f + expf(-blc[b * NCORE + m] * 0.2f));

        float ox, oy, oz;
        if (k == 0) {
            ox = tpose[0]; oy = tpose[1]; oz = tpose[2];
        } else {
            ox = (tpose[k * 3 + 0] - tpose[p * 3 + 0]) * f;
            oy = (tpose[k * 3 + 1] - tpose[p * 3 + 1]) * f;
            oz = (tpose[k * 3 + 2] - tpose[p * 3 + 2]) * f;
        }
        Asm[w][k][0] = r00; Asm[w][k][1] = r01; Asm[w][k][2]  = r02; Asm[w][k][3]  = ox;
        Asm[w][k][4] = r10; Asm[w][k][5] = r11; Asm[w][k][6]  = r12; Asm[w][k][7]  = oy;
        Asm[w][k][8] = r20; Asm[w][k][9] = r21; Asm[w][k][10] = r22; Asm[w][k][11] = oz;
    }
    __syncthreads();

    if (k == 0) {
        #pragma unroll
        for (int j = 0; j < 12; ++j) Gsm[w][0][j] = Asm[w][0][j];
    }
    __syncthreads();

    const int depth = (k < NJ) ? (31 - __clz((unsigned)(k + 1))) : 99;
    for (int d = 1; d <= 5; ++d) {
        if (depth == d) {
            float gp[12], a[12], g[12];
            #pragma unroll
            for (int j = 0; j < 12; ++j) { gp[j] = Gsm[w][p][j]; a[j] = Asm[w][k][j]; }
            #pragma unroll
            for (int i = 0; i < 3; ++i) {
                #pragma unroll
                for (int j = 0; j < 4; ++j) {
                    float s = (j == 3) ? gp[i * 4 + 3] : 0.0f;
                    s = fmaf(gp[i * 4 + 0], a[0 * 4 + j], s);
                    s = fmaf(gp[i * 4 + 1], a[1 * 4 + j], s);
                    s = fmaf(gp[i * 4 + 2], a[2 * 4 + j], s);
                    g[i * 4 + j] = s;
                }
            }
            #pragma unroll
            for (int j = 0; j < 12; ++j) Gsm[w][k][j] = g[j];
        }
        __syncthreads();
    }

    if (k < NJ) {
        float g[12];
        #pragma unroll
        for (int j = 0; j < 12; ++j) g[j] = Gsm[w][k][j];
        const float jx = tpose[k * 3 + 0];
        const float jy = tpose[k * 3 + 1];
        const float jz = tpose[k * 3 + 2];
        const float s  = scale[b];
        Jout[(b * NJ + k) * 3 + 0] = fmaf(g[3],  s, trans[b * 3 + 0]);
        Jout[(b * NJ + k) * 3 + 1] = fmaf(g[7],  s, trans[b * 3 + 1]);
        Jout[(b * NJ + k) * 3 + 2] = fmaf(g[11], s, trans[b * 3 + 2]);
        float np[3];
        np[0] = g[3]  - (g[0] * jx + g[1] * jy + g[2]  * jz);
        np[1] = g[7]  - (g[4] * jx + g[5] * jy + g[6]  * jz);
        np[2] = g[11] - (g[8] * jx + g[9] * jy + g[10] * jz);
        #pragma unroll
        for (int i = 0; i < 3; ++i) {
            short4v o;
            o[0] = f2bf(g[i * 4 + 0]);
            o[1] = f2bf(g[i * 4 + 1]);
            o[2] = f2bf(g[i * 4 + 2]);
            o[3] = f2bf(np[i]);
            *(short4v*)&Bt[(size_t)(b * 3 + i) * KPAD + k * 4] = o;
        }
        if (k == 0) {   // zero K padding cols 248..255
            short4v z = {0, 0, 0, 0};
            #pragma unroll
            for (int i = 0; i < 3; ++i) {
                *(short4v*)&Bt[(size_t)(b * 3 + i) * KPAD + 248] = z;
                *(short4v*)&Bt[(size_t)(b * 3 + i) * KPAD + 252] = z;
            }
        }
    }
}

// Flush one group of GSZ tiles: per region, GSZ*192B sequential floats.
// Division by (GSZ*24) is by a compile-time constant.
#define FLUSH(GSZ, GBASE)                                                     \
    {                                                                         \
        _Pragma("unroll")                                                     \
        for (int fi = 0; fi < (GSZ) * 6; ++fi) {                              \
            const int idx = fi * 64 + lane;                                   \
            const int rr  = idx / ((GSZ) * 24);                               \
            const int j2  = idx - rr * ((GSZ) * 24);                          \
            const floatx2 val = *(const floatx2*)&epi[rr * 200 + 2 * j2];     \
            const int pp = (GBASE) * 48 + 2 * j2;                             \
            if (pp + 1 < OUTF)                                                \
                *(floatx2*)&out[(size_t)(b0 + rr) * OUTF + pp] = val;         \
        }                                                                     \
    }

// ---------------------------------------------------------------------------
// Kernel 2: GEMM + epilogue, A built on the fly (r9 compute, unchanged).
// CHANGE: epilogue output buffered 4 tiles deep in LDS, flushed as 768B
// sequential runs per batch-region (was 192B interleaved) -> HBM row
// locality, no partial-line RMW churn. Grid 512 x 256 thr, 2 blocks/CU.
// ---------------------------------------------------------------------------
__global__ __launch_bounds__(256, 2) void gemm_skin(
    const float* __restrict__ W,      // (V, 62) fp32
    const float* __restrict__ vt,     // (V, 3)  fp32
    const short* __restrict__ Bt,     // (768, KPAD) bf16
    const float* __restrict__ scale,  // (B,)
    const float* __restrict__ trans,  // (B*3,)
    float* __restrict__ out)          // (B, V, 3)
{
    __shared__ __align__(16) float epi_all[4 * 3200];   // 51.2 KB

    const int tid  = threadIdx.x;
    const int wave = tid >> 6;
    const int lane = tid & 63;
    const int lrow = lane & 15;
    const int lk   = lane >> 4;
    const int y     = blockIdx.x >> 5;          // 0..15
    const int inner = blockIdx.x & 31;          // 0..31
    const int s     = inner * 4 + wave;         // stripe 0..127 (block-consecutive)
    const int start  = s * 7 + (s < 12 ? s : 12);
    const int ntiles = 7 + (s < 12 ? 1 : 0);
    const int b0 = y * 16;
    float* epi = epi_all + wave * 3200;         // 16 regions x 200 floats

    // ---- B slab -> registers, straight from global (L2-hot, loaded once)
    short8v breg[3][8];
    {
        const short* Bw = Bt + (size_t)y * 48 * KPAD;
        #pragma unroll
        for (int nt = 0; nt < 3; ++nt)
            #pragma unroll
            for (int k8 = 0; k8 < 8; ++k8)
                breg[nt][k8] = *(const short8v*)(Bw + (nt * 16 + lrow) * KPAD
                                                 + (k8 * 4 + lk) * 8);
    }

    // ---- per-thread invariants
    float sv[3], tv[3]; int bl3[3], ii3[3];
    #pragma unroll
    for (int nt = 0; nt < 3; ++nt) {
        const int n_loc = nt * 16 + lrow;
        bl3[nt] = n_loc / 3; ii3[nt] = n_loc - bl3[nt] * 3;
        sv[nt] = scale[b0 + bl3[nt]];
        tv[nt] = trans[(b0 + bl3[nt]) * 3 + ii3[nt]];
    }

    for (int t = 0; t < ntiles; ++t) {
        const int mtile = start + t;
        int vrow = mtile * 16 + lrow;
        if (vrow > NV - 1) vrow = NV - 1;           // pad rows: never stored
        const float hx = vt[vrow * 3 + 0];
        const float hy = vt[vrow * 3 + 1];
        const float hz = vt[vrow * 3 + 2];
        const float* Wr = W + (size_t)vrow * NJ;

        floatx4 acc[3];
        #pragma unroll
        for (int nt = 0; nt < 3; ++nt) acc[nt] = (floatx4){0.f, 0.f, 0.f, 0.f};

        #pragma unroll
        for (int k8 = 0; k8 < 8; ++k8) {
            const int j0 = k8 * 8 + lk * 2;         // joint pair (j0, j0+1)
            float w0 = 0.f, w1 = 0.f;
            if (j0 < NJ) {                          // j0==62 only for lk=3,k8=7
                const floatx2 wv = *(const floatx2*)(Wr + j0);  // 8B-aligned
                w0 = wv[0]; w1 = wv[1];
            }
            const short8v a = pack8(w0 * hx, w0 * hy, w0 * hz, w0,
                                    w1 * hx, w1 * hy, w1 * hz, w1);
            #pragma unroll
            for (int nt = 0; nt < 3; ++nt)
                acc[nt] = __builtin_amdgcn_mfma_f32_16x16x32_bf16(
                    a, breg[nt][k8], acc[nt], 0, 0, 0);
        }

        // ---- epilogue transpose into slot q of the 4-deep buffer
        const int q = t & 3;                        // groups {0..3}, {4..7}
        #pragma unroll
        for (int nt = 0; nt < 3; ++nt) {
            #pragma unroll
            for (int r = 0; r < 4; ++r)
                epi[bl3[nt] * 200 + q * 48 + (lk * 4 + r) * 3 + ii3[nt]] =
                    fmaf(acc[nt][r], sv[nt], tv[nt]);
        }

        // ---- flush at group boundaries: 768B (or 576B tail) per region
        if (t == 3) FLUSH(4, start);
    }
    if (ntiles == 8) { FLUSH(4, start + 4) }
    else             { FLUSH(3, start + 4) }
}

extern "C" void kernel_launch(void* const* d_in, const int* in_sizes, int n_in,
                              void* d_out, int out_size, void* d_ws, size_t ws_size,
                              hipStream_t stream)
{
    const float* thetas  = (const float*)d_in[0];
    const float* blc     = (const float*)d_in[1];
    const float* cbl     = (const float*)d_in[2];
    const float* trans   = (const float*)d_in[3];
    const float* scale   = (const float*)d_in[4];
    const float* vtempl  = (const float*)d_in[5];
    const float* tpose   = (const float*)d_in[6];
    const float* weights = (const float*)d_in[7];
    const int*   parents = (const int*)d_in[8];
    const int*   mapper  = (const int*)d_in[9];

    float* out  = (float*)d_out;
    float* Jout = out + (size_t)256 * NV * 3;

    short* Bt = (short*)d_ws;                    // 768*KPAD bf16 = 0.39 MB

    fk_kernel<<<64, 256, 0, stream>>>(thetas, blc, cbl, trans, scale, tpose,
                                      parents, mapper, Bt, Jout);
    gemm_skin<<<512, 256, 0, stream>>>(weights, vtempl, Bt, scale, trans, out);
}

// Round 12
// 26.389 us; speedup vs baseline: 1.4876x; 1.1677x over previous
//
#include <hip/hip_runtime.h>

#define NJ     62
#define NV     14522
#define NCORE  28
#define KPAD   256    // 62*4 = 248 padded to 256 (512 B per row)
#define OUTF   (NV * 3)        // 43566
#define MT     908             // m-tiles of 16 rows
#define NSTR   192             // stripes: 140 of 5 tiles, 52 of 4

typedef __attribute__((ext_vector_type(8))) short short8v;
typedef __attribute__((ext_vector_type(4))) short short4v;
typedef __attribute__((ext_vector_type(4))) float floatx4;
typedef __attribute__((ext_vector_type(2))) float floatx2;

#define AS1(p) ((const __attribute__((address_space(1))) void*)(p))
#define AS3(p) ((__attribute__((address_space(3))) void*)(p))

#define SCHED0() __builtin_amdgcn_sched_barrier(0)
#define WAITVM0() do { SCHED0(); asm volatile("s_waitcnt vmcnt(0)" ::: "memory"); SCHED0(); } while (0)

static __device__ inline short f2bf(float x) {
    unsigned u = __float_as_uint(x);
    unsigned r = (u + 0x7fffu + ((u >> 16) & 1u)) >> 16;
    return (short)r;
}

// pack 8 floats -> 8 bf16 (RNE) via v_cvt_pk_bf16_f32
static __device__ inline short8v pack8(float a0, float a1, float a2, float a3,
                                       float a4, float a5, float a6, float a7) {
    union { unsigned u[4]; short8v v; } p;
    asm("v_cvt_pk_bf16_f32 %0, %1, %2" : "=v"(p.u[0]) : "v"(a0), "v"(a1));
    asm("v_cvt_pk_bf16_f32 %0, %1, %2" : "=v"(p.u[1]) : "v"(a2), "v"(a3));
    asm("v_cvt_pk_bf16_f32 %0, %1, %2" : "=v"(p.u[2]) : "v"(a4), "v"(a5));
    asm("v_cvt_pk_bf16_f32 %0, %1, %2" : "=v"(p.u[3]) : "v"(a6), "v"(a7));
    return p.v;
}

// XOR swizzle over 512B rows: involution; applied to global SOURCE at staging
// and to LDS read addresses (both-sides rule). Proven in r6.
static __device__ inline unsigned swz(unsigned off) {
    return off ^ (((off >> 9) & 7u) << 4);
}

// ---------------------------------------------------------------------------
// Kernel 1: forward kinematics. 64 blocks x 256 thr; wave w = batch
// blockIdx*4+w. Writes Jout (fp32) and Bt[(b*3+i)*KPAD + 4k+j] = G' (bf16).
// ---------------------------------------------------------------------------
__global__ __launch_bounds__(256) void fk_kernel(
    const float* __restrict__ thetas, const float* __restrict__ blc,
    const float* __restrict__ cbl, const float* __restrict__ trans,
    const float* __restrict__ scale, const float* __restrict__ tpose,
    const int* __restrict__ parents, const int* __restrict__ mapper,
    short* __restrict__ Bt, float* __restrict__ Jout)
{
    __shared__ float Asm[4][NJ][12];
    __shared__ float Gsm[4][NJ][12];

    const int w = threadIdx.x >> 6;
    const int b = blockIdx.x * 4 + w;
    const int k = threadIdx.x & 63;
    int p = 0;

    if (k < NJ) {
        p = parents[k];
        const float tz = thetas[(b * NJ + k) * 3 + 0];
        const float ty = thetas[(b * NJ + k) * 3 + 1];
        const float tx = thetas[(b * NJ + k) * 3 + 2];
        const float cx = cosf(tx), sx = sinf(tx);
        const float cy = cosf(ty), sy = sinf(ty);
        const float cz = cosf(tz), sz = sinf(tz);
        const float r00 = cz * cy;
        const float r01 = cz * sy * sx - sz * cx;
        const float r02 = sz * sx + cz * sy * cx;
        const float r10 = sz * cy;
        const float r11 = cz * cx + sz * sy * sx;
        const float r12 = sz * sy * cx - cz * sx;
        const float r20 = -sy;
        const float r21 = cy * sx;
        const float r22 = cy * cx;

        float f;
        const int m = mapper[k];
        if (k == 0)        f = 1.0f;
        else if (k == 1)   f = cbl[b];
        else if (m < 0)    f = 1.0f;
        else               f = 2.0f / (1.0f + expf(-blc[b * NCORE + m] * 0.2f));

        float ox, oy, oz;
        if (k == 0) {
            ox = tpose[0]; oy = tpose[1]; oz = tpose[2];
        } else {
            ox = (tpose[k * 3 + 0] - tpose[p * 3 + 0]) * f;
            oy = (tpose[k * 3 + 1] - tpose[p * 3 + 1]) * f;
            oz = (tpose[k * 3 + 2] - tpose[p * 3 + 2]) * f;
        }
        Asm[w][k][0] = r00; Asm[w][k][1] = r01; Asm[w][k][2]  = r02; Asm[w][k][3]  = ox;
        Asm[w][k][4] = r10; Asm[w][k][5] = r11; Asm[w][k][6]  = r12; Asm[w][k][7]  = oy;
        Asm[w][k][8] = r20; Asm[w][k][9] = r21; Asm[w][k][10] = r22; Asm[w][k][11] = oz;
    }
    __syncthreads();

    if (k == 0) {
        #pragma unroll
        for (int j = 0; j < 12; ++j) Gsm[w][0][j] = Asm[w][0][j];
    }
    __syncthreads();

    const int depth = (k < NJ) ? (31 - __clz((unsigned)(k + 1))) : 99;
    for (int d = 1; d <= 5; ++d) {
        if (depth == d) {
            float gp[12], a[12], g[12];
            #pragma unroll
            for (int j = 0; j < 12; ++j) { gp[j] = Gsm[w][p][j]; a[j] = Asm[w][k][j]; }
            #pragma unroll
            for (int i = 0; i < 3; ++i) {
                #pragma unroll
                for (int j = 0; j < 4; ++j) {
                    float s = (j == 3) ? gp[i * 4 + 3] : 0.0f;
                    s = fmaf(gp[i * 4 + 0], a[0 * 4 + j], s);
                    s = fmaf(gp[i * 4 + 1], a[1 * 4 + j], s);
                    s = fmaf(gp[i * 4 + 2], a[2 * 4 + j], s);
                    g[i * 4 + j] = s;
                }
            }
            #pragma unroll
            for (int j = 0; j < 12; ++j) Gsm[w][k][j] = g[j];
        }
        __syncthreads();
    }

    if (k < NJ) {
        float g[12];
        #pragma unroll
        for (int j = 0; j < 12; ++j) g[j] = Gsm[w][k][j];
        const float jx = tpose[k * 3 + 0];
        const float jy = tpose[k * 3 + 1];
        const float jz = tpose[k * 3 + 2];
        const float s  = scale[b];
        Jout[(b * NJ + k) * 3 + 0] = fmaf(g[3],  s, trans[b * 3 + 0]);
        Jout[(b * NJ + k) * 3 + 1] = fmaf(g[7],  s, trans[b * 3 + 1]);
        Jout[(b * NJ + k) * 3 + 2] = fmaf(g[11], s, trans[b * 3 + 2]);
        float np[3];
        np[0] = g[3]  - (g[0] * jx + g[1] * jy + g[2]  * jz);
        np[1] = g[7]  - (g[4] * jx + g[5] * jy + g[6]  * jz);
        np[2] = g[11] - (g[8] * jx + g[9] * jy + g[10] * jz);
        #pragma unroll
        for (int i = 0; i < 3; ++i) {
            short4v o;
            o[0] = f2bf(g[i * 4 + 0]);
            o[1] = f2bf(g[i * 4 + 1]);
            o[2] = f2bf(g[i * 4 + 2]);
            o[3] = f2bf(np[i]);
            *(short4v*)&Bt[(size_t)(b * 3 + i) * KPAD + k * 4] = o;
        }
        if (k == 0) {   // zero K padding cols 248..255
            short4v z = {0, 0, 0, 0};
            #pragma unroll
            for (int i = 0; i < 3; ++i) {
                *(short4v*)&Bt[(size_t)(b * 3 + i) * KPAD + 248] = z;
                *(short4v*)&Bt[(size_t)(b * 3 + i) * KPAD + 252] = z;
            }
        }
    }
}

// ---------------------------------------------------------------------------
// Kernel 2: GEMM + epilogue, A on the fly (r9 compute), OCCUPANCY FIX:
// B-slab moved from 96 VGPRs to LDS (24 KB/block, staged once, swizzled)
// -> VGPR ~<=168 with no spill -> 3 waves/SIMD (12 waves/CU, 1.5x r9).
// Grid 768 = 3 blocks/CU exactly resident (no tail). 192 stripes x 16 y.
// Per tile: 8 scattered W float2 + pack -> A frags; 24 swizzled ds_read_b128
// B frags; 24 MFMA; wave-private LDS epi transpose; coalesced float2 stores.
// ---------------------------------------------------------------------------
__global__ __launch_bounds__(256, 3) void gemm_skin(
    const float* __restrict__ W,      // (V, 62) fp32
    const float* __restrict__ vt,     // (V, 3)  fp32
    const short* __restrict__ Bt,     // (768, KPAD) bf16
    const float* __restrict__ scale,  // (B,)
    const float* __restrict__ trans,  // (B*3,)
    float* __restrict__ out)          // (B, V, 3)
{
    __shared__ __align__(16) char ldsB[48 * 512];       // 24 KB B slab
    __shared__ __align__(16) float epi_all[4 * 800];    // 12.8 KB epi

    const int tid  = threadIdx.x;
    const int wave = tid >> 6;
    const int lane = tid & 63;
    const int lrow = lane & 15;
    const int lk   = lane >> 4;
    const int yy    = blockIdx.x / 48;          // 0..15 (y-group)
    const int inner = blockIdx.x - yy * 48;     // 0..47
    const int s     = inner * 4 + wave;         // stripe 0..191
    const int start  = s * 4 + (s < 140 ? s : 140);
    const int ntiles = 4 + (s < 140 ? 1 : 0);
    const int b0 = yy * 16;
    float* epi = epi_all + wave * 800;          // 16 regions x 50 floats

    // ---- stage B slab into LDS once (global_load_lds, both-sides swizzle)
    {
        const char* Bsrc = (const char*)(Bt + (size_t)yy * 48 * KPAD);
        #pragma unroll
        for (int cc = 0; cc < 6; ++cc) {
            const unsigned Lb = (unsigned)(wave * 6144 + cc * 1024);
            __builtin_amdgcn_global_load_lds(AS1(Bsrc + swz(Lb + lane * 16)),
                                             AS3(ldsB + Lb), 16, 0, 0);
        }
    }

    // ---- per-thread invariants (computed while DMA is in flight)
    float sv[3], tv[3]; int bl3[3], ii3[3];
    #pragma unroll
    for (int nt = 0; nt < 3; ++nt) {
        const int n_loc = nt * 16 + lrow;
        bl3[nt] = n_loc / 3; ii3[nt] = n_loc - bl3[nt] * 3;
        sv[nt] = scale[b0 + bl3[nt]];
        tv[nt] = trans[(b0 + bl3[nt]) * 3 + ii3[nt]];
    }
    unsigned bofs[3], bxor[3];
    #pragma unroll
    for (int nt = 0; nt < 3; ++nt) {
        const unsigned brow = nt * 16 + lrow;
        bofs[nt] = brow * 512;
        bxor[nt] = (brow & 7u) << 4;
    }

    WAITVM0();
    __syncthreads();    // B slab resident; read-only hereafter (no more barriers)

    for (int t = 0; t < ntiles; ++t) {
        const int mtile = start + t;
        int vrow = mtile * 16 + lrow;
        if (vrow > NV - 1) vrow = NV - 1;           // pad rows: never stored
        const float hx = vt[vrow * 3 + 0];
        const float hy = vt[vrow * 3 + 1];
        const float hz = vt[vrow * 3 + 2];
        const float* Wr = W + (size_t)vrow * NJ;

        // ---- A frags on the fly (8 scattered float2 + pack)
        short8v af[8];
        #pragma unroll
        for (int k8 = 0; k8 < 8; ++k8) {
            const int j0 = k8 * 8 + lk * 2;         // joint pair (j0, j0+1)
            float w0 = 0.f, w1 = 0.f;
            if (j0 < NJ) {
                const floatx2 wv = *(const floatx2*)(Wr + j0);  // 8B-aligned
                w0 = wv[0]; w1 = wv[1];
            }
            af[k8] = pack8(w0 * hx, w0 * hy, w0 * hz, w0,
                           w1 * hx, w1 * hy, w1 * hz, w1);
        }

        // ---- MFMA: B frags from LDS (swizzled ds_read_b128)
        floatx4 acc[3];
        #pragma unroll
        for (int nt = 0; nt < 3; ++nt) acc[nt] = (floatx4){0.f, 0.f, 0.f, 0.f};
        #pragma unroll
        for (int k8 = 0; k8 < 8; ++k8) {
            const unsigned cb = (unsigned)(k8 * 4 + lk) * 16;
            #pragma unroll
            for (int nt = 0; nt < 3; ++nt) {
                const short8v bf = *(const short8v*)(ldsB + bofs[nt] + (cb ^ bxor[nt]));
                acc[nt] = __builtin_amdgcn_mfma_f32_16x16x32_bf16(
                    af[k8], bf, acc[nt], 0, 0, 0);
            }
        }

        // ---- epilogue transpose (wave-private region)
        #pragma unroll
        for (int nt = 0; nt < 3; ++nt) {
            #pragma unroll
            for (int r = 0; r < 4; ++r)
                epi[bl3[nt] * 50 + (lk * 4 + r) * 3 + ii3[nt]] =
                    fmaf(acc[nt][r], sv[nt], tv[nt]);
        }

        // ---- coalesced stores: 16 regions x 24 float2 (addresses inline)
        const int m48 = mtile * 48;
        const bool edge = (m48 + 48 > OUTF);
        #pragma unroll
        for (int it = 0; it < 6; ++it) {
            const int idx = it * 64 + lane;
            const int r = idx / 24, j = idx - r * 24;
            const floatx2 val = *(const floatx2*)&epi[r * 50 + 2 * j];
            const int pp = m48 + 2 * j;
            if (!edge || pp + 1 < OUTF)
                *(floatx2*)&out[(size_t)(b0 + r) * OUTF + pp] = val;
        }
    }
}

extern "C" void kernel_launch(void* const* d_in, const int* in_sizes, int n_in,
                              void* d_out, int out_size, void* d_ws, size_t ws_size,
                              hipStream_t stream)
{
    const float* thetas  = (const float*)d_in[0];
    const float* blc     = (const float*)d_in[1];
    const float* cbl     = (const float*)d_in[2];
    const float* trans   = (const float*)d_in[3];
    const float* scale   = (const float*)d_in[4];
    const float* vtempl  = (const float*)d_in[5];
    const float* tpose   = (const float*)d_in[6];
    const float* weights = (const float*)d_in[7];
    const int*   parents = (const int*)d_in[8];
    const int*   mapper  = (const int*)d_in[9];

    float* out  = (float*)d_out;
    float* Jout = out + (size_t)256 * NV * 3;

    short* Bt = (short*)d_ws;                    // 768*KPAD bf16 = 0.39 MB

    fk_kernel<<<64, 256, 0, stream>>>(thetas, blc, cbl, trans, scale, tpose,
                                      parents, mapper, Bt, Jout);
    gemm_skin<<<768, 256, 0, stream>>>(weights, vtempl, Bt, scale, trans, out);
}